// Round 1
// baseline (86437.140 us; speedup 1.0000x reference)
//
#include <hip/hip_runtime.h>

#define Tn   512
#define Dn   64
#define Hn   512
#define BBn  8
#define KIN  128   // 2*D (concat of values, mask)
#define KTOT 640   // KIN + Hn

// ---- bf16 helpers (manual, RNE) ----
__device__ __forceinline__ unsigned short f2bf(float f) {
  unsigned u = __float_as_uint(f);
  unsigned r = u + 0x7fffu + ((u >> 16) & 1u);
  return (unsigned short)(r >> 16);
}

// Pre-pass: build transposed, gate-interleaved bf16 weights in workspace.
// WT_rz[k*Hn + j] = pack(bf16(W_r[j][k]), bf16(W_z[j][k]))  (r in low 16, z in high 16)
// WT_n [k*Hn + j] = bf16(W_n[j][k])
// where rows of W_cat: [0,H)=r, [H,2H)=z, [2H,3H)=n; cols: k<128 -> W_ih, else W_hh.
__global__ __launch_bounds__(256) void cru_prep(
    const float* __restrict__ W_ih, const float* __restrict__ W_hh,
    unsigned int* __restrict__ WT_rz, unsigned short* __restrict__ WT_n)
{
  int idx = blockIdx.x * 256 + threadIdx.x;
  if (idx >= KTOT * Hn) return;
  int k = idx >> 9;        // 0..639
  int j = idx & (Hn - 1);  // 0..511
  float sr, sz, sn;
  if (k < KIN) {
    sr = W_ih[j * KIN + k];
    sz = W_ih[(j + Hn) * KIN + k];
    sn = W_ih[(j + 2 * Hn) * KIN + k];
  } else {
    int kk = k - KIN;
    sr = W_hh[j * Hn + kk];
    sz = W_hh[(j + Hn) * Hn + kk];
    sn = W_hh[(j + 2 * Hn) * Hn + kk];
  }
  WT_rz[idx] = (unsigned)f2bf(sr) | ((unsigned)f2bf(sz) << 16);
  WT_n[idx]  = f2bf(sn);
}

// Main: one block per 8 batch rows, runs the entire T=512 recurrence.
// 512 threads: thread jh owns output column jh for all 8 rows.
__global__ __launch_bounds__(512) void cru_main(
    const float* __restrict__ values, const float* __restrict__ mask,
    const float* __restrict__ tsp,
    const float* __restrict__ b_ih, const float* __restrict__ b_hh,
    const float* __restrict__ W_decay, const float* __restrict__ b_decay,
    const float* __restrict__ W_head, const float* __restrict__ b_head,
    const unsigned int* __restrict__ WT_rz, const unsigned short* __restrict__ WT_n,
    float* __restrict__ out)
{
  __shared__ float sh[BBn][Hn];    // hidden state (fp32)
  __shared__ float sx[BBn][KIN];   // current-step input [v|m]
  __shared__ float sts[BBn][Tn];   // timestamps for this block's rows
  __shared__ float swd[Hn];
  __shared__ float sbd[Hn];

  const int tid = threadIdx.x;
  const int b0  = blockIdx.x * BBn;
  const int jh  = tid;             // 0..511

  // preload timestamps (coalesced), decay params, zero h
  for (int i = tid; i < BBn * Tn; i += 512) {
    int bl = i >> 9; int t = i & (Tn - 1);
    sts[bl][t] = tsp[(b0 + bl) * Tn + t];
  }
  if (tid < Hn) { swd[tid] = W_decay[tid]; sbd[tid] = b_decay[tid]; }
  for (int i = tid; i < BBn * Hn; i += 512) ((float*)sh)[i] = 0.0f;

  // per-thread constant biases
  const float bR  = b_ih[jh] + b_hh[jh];
  const float bZ  = b_ih[jh + Hn] + b_hh[jh + Hn];
  const float bIN = b_ih[jh + 2 * Hn];
  const float bHN = b_hh[jh + 2 * Hn];

  const int bl8 = tid >> 6;   // 0..7 : batch row this thread stages/decays
  const int d64 = tid & 63;

  __syncthreads();

  for (int t = 0; t < Tn; ++t) {
    // stage input: each thread loads 1 value + 1 mask element (coalesced)
    {
      size_t base = ((size_t)(b0 + bl8) * Tn + t) * Dn + d64;
      sx[bl8][d64]      = values[base];
      sx[bl8][Dn + d64] = mask[base];
    }
    // apply decay in-place: h *= exp(-softplus(dt*Wd + bd)); skip t==0 (h==h0)
    if (t > 0) {
      float dt = sts[bl8][t] - sts[bl8][t - 1];
      #pragma unroll
      for (int u = 0; u < 8; ++u) {
        int k = d64 + 64 * u;
        float pre = fmaf(dt, swd[k], sbd[k]);
        float sp  = fmaxf(pre, 0.0f) + log1pf(__expf(-fabsf(pre)));
        sh[bl8][k] *= __expf(-sp);
      }
    }
    __syncthreads();

    float aR[BBn], aZ[BBn], aIN[BBn], aHN[BBn];
    #pragma unroll
    for (int b = 0; b < BBn; ++b) { aR[b] = bR; aZ[b] = bZ; aIN[b] = bIN; aHN[b] = bHN; }

    // ---- input part: k in [0,128) over sx ----
    for (int k0 = 0; k0 < KIN; k0 += 4) {
      float wr[4], wz[4], wn[4];
      #pragma unroll
      for (int i = 0; i < 4; ++i) {
        unsigned int w = WT_rz[(k0 + i) * Hn + jh];
        wr[i] = __uint_as_float(w << 16);
        wz[i] = __uint_as_float(w & 0xffff0000u);
        wn[i] = __uint_as_float((unsigned)WT_n[(k0 + i) * Hn + jh] << 16);
      }
      #pragma unroll
      for (int b = 0; b < BBn; ++b) {
        const float4 x = *(const float4*)&sx[b][k0];
        float xr[4] = {x.x, x.y, x.z, x.w};
        #pragma unroll
        for (int i = 0; i < 4; ++i) {
          aR[b]  = fmaf(xr[i], wr[i], aR[b]);
          aZ[b]  = fmaf(xr[i], wz[i], aZ[b]);
          aIN[b] = fmaf(xr[i], wn[i], aIN[b]);
        }
      }
    }
    // ---- hidden part: k in [0,512) over sh (already decayed) ----
    for (int k0 = 0; k0 < Hn; k0 += 4) {
      float wr[4], wz[4], wn[4];
      #pragma unroll
      for (int i = 0; i < 4; ++i) {
        unsigned int w = WT_rz[(KIN + k0 + i) * Hn + jh];
        wr[i] = __uint_as_float(w << 16);
        wz[i] = __uint_as_float(w & 0xffff0000u);
        wn[i] = __uint_as_float((unsigned)WT_n[(KIN + k0 + i) * Hn + jh] << 16);
      }
      #pragma unroll
      for (int b = 0; b < BBn; ++b) {
        const float4 hv = *(const float4*)&sh[b][k0];
        float hr[4] = {hv.x, hv.y, hv.z, hv.w};
        #pragma unroll
        for (int i = 0; i < 4; ++i) {
          aR[b]  = fmaf(hr[i], wr[i], aR[b]);
          aZ[b]  = fmaf(hr[i], wz[i], aZ[b]);
          aHN[b] = fmaf(hr[i], wn[i], aHN[b]);
        }
      }
    }

    // gates + state update (hold h_new in regs until all reads of sh are done)
    float hnew[BBn];
    #pragma unroll
    for (int b = 0; b < BBn; ++b) {
      float r = 1.0f / (1.0f + __expf(-aR[b]));
      float z = 1.0f / (1.0f + __expf(-aZ[b]));
      float n = tanhf(fmaf(r, aHN[b], aIN[b]));
      hnew[b] = (1.0f - z) * n + z * sh[b][jh];
    }
    __syncthreads();
    #pragma unroll
    for (int b = 0; b < BBn; ++b) sh[b][jh] = hnew[b];
    __syncthreads();
  }

  // head: out[b][nt] = h_T . W_head[nt] + b_head[nt]   (tiny)
  if (tid < BBn * 8) {
    int b = tid >> 3; int nt = tid & 7;
    float a = b_head[nt];
    for (int k = 0; k < Hn; ++k) a = fmaf(sh[b][k], W_head[nt * Hn + k], a);
    out[(size_t)(b0 + b) * 8 + nt] = a;
  }
}

extern "C" void kernel_launch(void* const* d_in, const int* in_sizes, int n_in,
                              void* d_out, int out_size, void* d_ws, size_t ws_size,
                              hipStream_t stream)
{
  const float* values  = (const float*)d_in[0];
  const float* mask    = (const float*)d_in[1];
  const float* tsp     = (const float*)d_in[2];
  const float* W_ih    = (const float*)d_in[3];
  const float* W_hh    = (const float*)d_in[4];
  const float* b_ih    = (const float*)d_in[5];
  const float* b_hh    = (const float*)d_in[6];
  const float* W_decay = (const float*)d_in[7];
  const float* b_decay = (const float*)d_in[8];
  const float* W_head  = (const float*)d_in[9];
  const float* b_head  = (const float*)d_in[10];
  float* out = (float*)d_out;

  unsigned int*   WT_rz = (unsigned int*)d_ws;                                  // 640*512*4 B
  unsigned short* WT_n  = (unsigned short*)((char*)d_ws + (size_t)KTOT * Hn * 4); // +640*512*2 B

  int total = KTOT * Hn;
  cru_prep<<<(total + 255) / 256, 256, 0, stream>>>(W_ih, W_hh, WT_rz, WT_n);
  cru_main<<<2048 / BBn, 512, 0, stream>>>(values, mask, tsp, b_ih, b_hh,
      W_decay, b_decay, W_head, b_head, WT_rz, WT_n, out);
}

// Round 2
// 42381.958 us; speedup vs baseline: 2.0395x; 2.0395x over previous
//
#include <hip/hip_runtime.h>

#define Tn     512
#define Dn     64
#define Hn     512
#define BB     16
#define KSTEPS 20              // 640 / 32
#define NFRAG  (KSTEPS * 64)   // A/B frags per tile-column
#define SHS    516             // sh row stride (fp32), +4 pad -> 2-way banks (free)

typedef __attribute__((ext_vector_type(8))) short  short8;   // 8 bf16 (4 VGPRs)
typedef __attribute__((ext_vector_type(4))) float  floatx4;  // MFMA acc

__device__ __forceinline__ unsigned short f2bf(float f) {
  unsigned u = __float_as_uint(f);
  unsigned r = u + 0x7fffu + ((u >> 16) & 1u);
  return (unsigned short)(r >> 16);
}
__device__ __forceinline__ float frcp(float x) { return __builtin_amdgcn_rcpf(x); }
__device__ __forceinline__ float sigm(float x) { return frcp(1.f + __expf(-x)); }
__device__ __forceinline__ float tanhfast(float y) {
  float a = fabsf(y);
  float e = __expf(-2.f * a);                 // e <= 1, no overflow
  float m = 1.f - 2.f * e * frcp(1.f + e);
  return copysignf(m, y);
}

// ---------------------------------------------------------------------------
// Prep: pack W_cat^T (B-operand) into exact MFMA B-fragment order, bf16.
// WB[tile][ks][lane][j]  =  W_cat[n = tile*16 + (lane&15)][k = ks*32 + (lane>>4)*8 + j]
// tile 0..95 (96*16 = 1536 gate outputs: [0,512)=r, [512,1024)=z, [1024,1536)=n)
// k: 0..127 -> W_ih cols, 128..639 -> W_hh cols.
// ---------------------------------------------------------------------------
__global__ __launch_bounds__(256) void cru_prep(
    const float* __restrict__ W_ih, const float* __restrict__ W_hh,
    short8* __restrict__ WB)
{
  int idx = blockIdx.x * 256 + threadIdx.x;          // one fragment (8 bf16) each
  if (idx >= 96 * NFRAG) return;
  int nt   = idx / NFRAG;
  int rem  = idx % NFRAG;
  int ks   = rem >> 6;
  int lane = rem & 63;
  int lc   = lane & 15, quad = lane >> 4;
  int n  = nt * 16 + lc;
  int k0 = ks * 32 + quad * 8;
  const float* src = (k0 < 128) ? (W_ih + (size_t)n * 128 + k0)
                                : (W_hh + (size_t)n * 512 + (k0 - 128));
  float4 x0 = ((const float4*)src)[0];
  float4 x1 = ((const float4*)src)[1];
  union { unsigned short us[8]; short8 v; } pk;
  pk.us[0] = f2bf(x0.x); pk.us[1] = f2bf(x0.y); pk.us[2] = f2bf(x0.z); pk.us[3] = f2bf(x0.w);
  pk.us[4] = f2bf(x1.x); pk.us[5] = f2bf(x1.y); pk.us[6] = f2bf(x1.z); pk.us[7] = f2bf(x1.w);
  WB[idx] = pk.v;
}

// ---------------------------------------------------------------------------
// Main: 128 blocks x 512 threads (8 waves). Block owns 16 batch rows, runs all
// T=512 steps. Wave w owns h-columns [w*64, w*64+64) of each gate (tile-triples
// r/z/n share the thread->(m,j) mapping, so gates combine in registers).
// ---------------------------------------------------------------------------
__global__ __launch_bounds__(512, 2) void cru_main(
    const float* __restrict__ values, const float* __restrict__ maskp,
    const float* __restrict__ tsp,
    const float* __restrict__ b_ih, const float* __restrict__ b_hh,
    const float* __restrict__ W_decay, const float* __restrict__ b_decay,
    const float* __restrict__ W_head, const float* __restrict__ b_head,
    const short8* __restrict__ WB,
    float* __restrict__ out)
{
  __shared__ float  sh[BB][SHS];        // fp32 master hidden state
  __shared__ short8 apk[NFRAG];         // A fragments (bf16), rebuilt per step

  const int tid  = threadIdx.x;
  const int b0   = blockIdx.x * BB;
  const int w    = tid >> 6;
  const int lane = tid & 63;
  const int quad = lane >> 4;
  const int lc   = lane & 15;

  for (int i = tid; i < BB * SHS; i += 512) (&sh[0][0])[i] = 0.f;

  // per-thread constants for the 4 tile-triples: j = w*64 + k*16 + lc
  float bR[4], bZ[4], bIN[4], bHN[4], wdc[4], bdc[4];
  #pragma unroll
  for (int k = 0; k < 4; ++k) {
    int j = w * 64 + k * 16 + lc;
    bR[k]  = b_ih[j]        + b_hh[j];
    bZ[k]  = b_ih[j + 512]  + b_hh[j + 512];
    bIN[k] = b_ih[j + 1024];
    bHN[k] = b_hh[j + 1024];
    wdc[k] = W_decay[j];
    bdc[k] = b_decay[j];
  }

  const short8* WBr = WB + ((size_t)(w * 4)      * KSTEPS) * 64 + lane;
  const short8* WBz = WB + ((size_t)(32 + w * 4) * KSTEPS) * 64 + lane;
  const short8* WBn = WB + ((size_t)(64 + w * 4) * KSTEPS) * 64 + lane;

  __syncthreads();

  for (int t = 0; t < Tn; ++t) {
    // ---- stage A fragments: [x(bf16) | h(bf16)] in exact A-operand order ----
    for (int s = tid; s < NFRAG; s += 512) {
      int ks = s >> 6, ln = s & 63;
      int m = ln & 15, qd = ln >> 4;
      int kg = ks * 32 + qd * 8;
      float4 x0, x1;
      if (ks < 4) {
        const float* src = (kg < 64)
          ? values + ((size_t)(b0 + m) * Tn + t) * Dn + kg
          : maskp  + ((size_t)(b0 + m) * Tn + t) * Dn + (kg - 64);
        x0 = ((const float4*)src)[0];
        x1 = ((const float4*)src)[1];
      } else {
        const float* src = &sh[m][kg - 128];   // sh already carries decay
        x0 = ((const float4*)src)[0];
        x1 = ((const float4*)src)[1];
      }
      union { unsigned short us[8]; short8 v; } pk;
      pk.us[0] = f2bf(x0.x); pk.us[1] = f2bf(x0.y); pk.us[2] = f2bf(x0.z); pk.us[3] = f2bf(x0.w);
      pk.us[4] = f2bf(x1.x); pk.us[5] = f2bf(x1.y); pk.us[6] = f2bf(x1.z); pk.us[7] = f2bf(x1.w);
      apk[s] = pk.v;
    }

    // prefetch next-step dt for the decay fold (hidden behind the GEMM)
    float dtq[4] = {0.f, 0.f, 0.f, 0.f};
    if (t + 1 < Tn) {
      #pragma unroll
      for (int q = 0; q < 4; ++q) {
        size_t rb = (size_t)(b0 + quad * 4 + q) * Tn;
        dtq[q] = tsp[rb + t + 1] - tsp[rb + t];
      }
    }
    __syncthreads();

    floatx4 accR[4], accZ[4], accIN[4], accHN[4];
    #pragma unroll
    for (int k = 0; k < 4; ++k) {
      accR[k]  = (floatx4){0.f, 0.f, 0.f, 0.f};
      accZ[k]  = (floatx4){0.f, 0.f, 0.f, 0.f};
      accIN[k] = (floatx4){0.f, 0.f, 0.f, 0.f};
      accHN[k] = (floatx4){0.f, 0.f, 0.f, 0.f};
    }

    // ---- K-loop, x part (k<128): n-gate goes to accIN ----
    for (int ks = 0; ks < 4; ++ks) {
      short8 av = apk[ks * 64 + lane];
      #pragma unroll
      for (int k = 0; k < 4; ++k) {
        short8 br = WBr[(k * KSTEPS + ks) * 64];
        short8 bz = WBz[(k * KSTEPS + ks) * 64];
        short8 bn = WBn[(k * KSTEPS + ks) * 64];
        accR[k]  = __builtin_amdgcn_mfma_f32_16x16x32_bf16(av, br, accR[k],  0, 0, 0);
        accZ[k]  = __builtin_amdgcn_mfma_f32_16x16x32_bf16(av, bz, accZ[k],  0, 0, 0);
        accIN[k] = __builtin_amdgcn_mfma_f32_16x16x32_bf16(av, bn, accIN[k], 0, 0, 0);
      }
    }
    // ---- K-loop, h part (k>=128): n-gate goes to accHN ----
    for (int ks = 4; ks < KSTEPS; ++ks) {
      short8 av = apk[ks * 64 + lane];
      #pragma unroll
      for (int k = 0; k < 4; ++k) {
        short8 br = WBr[(k * KSTEPS + ks) * 64];
        short8 bz = WBz[(k * KSTEPS + ks) * 64];
        short8 bn = WBn[(k * KSTEPS + ks) * 64];
        accR[k]  = __builtin_amdgcn_mfma_f32_16x16x32_bf16(av, br, accR[k],  0, 0, 0);
        accZ[k]  = __builtin_amdgcn_mfma_f32_16x16x32_bf16(av, bz, accZ[k],  0, 0, 0);
        accHN[k] = __builtin_amdgcn_mfma_f32_16x16x32_bf16(av, bn, accHN[k], 0, 0, 0);
      }
    }

    // ---- epilogue: gates + update + next-step decay, all in registers ----
    const bool last = (t == Tn - 1);
    #pragma unroll
    for (int k = 0; k < 4; ++k) {
      int j = w * 64 + k * 16 + lc;
      #pragma unroll
      for (int q = 0; q < 4; ++q) {
        int m = quad * 4 + q;
        float r  = sigm(accR[k][q] + bR[k]);
        float z  = sigm(accZ[k][q] + bZ[k]);
        float nn = tanhfast(accIN[k][q] + bIN[k] + r * (accHN[k][q] + bHN[k]));
        float hnew = (1.f - z) * nn + z * sh[m][j];
        if (!last) {
          float pre = fmaf(dtq[q], wdc[k], bdc[k]);
          hnew *= frcp(1.f + __expf(pre));     // exp(-softplus(pre))
        }
        sh[m][j] = hnew;
      }
    }
    __syncthreads();
  }

  // ---- head: out[b][nt] = h_T . W_head[nt] + b_head[nt] ----
  if (tid < BB * 8) {
    int b = tid >> 3, nt2 = tid & 7;
    float a = b_head[nt2];
    for (int k2 = 0; k2 < Hn; ++k2)
      a = fmaf(sh[b][k2], W_head[(size_t)nt2 * Hn + k2], a);
    out[(size_t)(b0 + b) * 8 + nt2] = a;
  }
}

extern "C" void kernel_launch(void* const* d_in, const int* in_sizes, int n_in,
                              void* d_out, int out_size, void* d_ws, size_t ws_size,
                              hipStream_t stream)
{
  const float* values  = (const float*)d_in[0];
  const float* mask    = (const float*)d_in[1];
  const float* tsp     = (const float*)d_in[2];
  const float* W_ih    = (const float*)d_in[3];
  const float* W_hh    = (const float*)d_in[4];
  const float* b_ih    = (const float*)d_in[5];
  const float* b_hh    = (const float*)d_in[6];
  const float* W_decay = (const float*)d_in[7];
  const float* b_decay = (const float*)d_in[8];
  const float* W_head  = (const float*)d_in[9];
  const float* b_head  = (const float*)d_in[10];
  float* out = (float*)d_out;

  short8* WB = (short8*)d_ws;   // 96*20*64 frags * 16 B = 1.97 MB

  int nfrag_total = 96 * NFRAG;
  cru_prep<<<(nfrag_total + 255) / 256, 256, 0, stream>>>(W_ih, W_hh, WB);
  cru_main<<<2048 / BB, 512, 0, stream>>>(values, mask, tsp, b_ih, b_hh,
      W_decay, b_decay, W_head, b_head, WB, out);
}

// Round 3
// 31030.530 us; speedup vs baseline: 2.7856x; 1.3658x over previous
//
#include <hip/hip_runtime.h>

#define Tn     512
#define Dn     64
#define Hn     512
#define BB     32              // batch rows per block -> 64 blocks
#define KSTEPS 20              // 640 / 32
#define SHS    516             // sh row stride (fp32): 16B-aligned, bank-friendly

typedef __attribute__((ext_vector_type(8))) short  short8;   // 8 bf16 (4 VGPRs)
typedef __attribute__((ext_vector_type(4))) float  floatx4;  // MFMA acc

__device__ __forceinline__ unsigned short f2bf(float f) {
  unsigned u = __float_as_uint(f);
  unsigned r = u + 0x7fffu + ((u >> 16) & 1u);
  return (unsigned short)(r >> 16);
}
__device__ __forceinline__ float frcp(float x) { return __builtin_amdgcn_rcpf(x); }
__device__ __forceinline__ float sigm(float x) { return frcp(1.f + __expf(-x)); }
__device__ __forceinline__ float tanhfast(float y) {
  float a = fabsf(y);
  float e = __expf(-2.f * a);
  float m = 1.f - 2.f * e * frcp(1.f + e);
  return copysignf(m, y);
}

// ---------------------------------------------------------------------------
// Prep: pack W_cat^T into per-wave-contiguous MFMA B-fragment order, bf16.
// Index: frag(ks, w, f, lane), f = g*4+t (g: 0=r,1=z,2=n; t: tile within wave)
//   flat = ((ks*8 + w)*12 + f)*64 + lane
// Element: col n = g*512 + w*64 + t*16 + (lane&15); k = ks*32 + (lane>>4)*8 + j
// k<128 -> W_ih, else W_hh. Total 20*8*12*64 frags * 16 B = 1.97 MB.
// ---------------------------------------------------------------------------
__global__ __launch_bounds__(256) void cru_prep(
    const float* __restrict__ W_ih, const float* __restrict__ W_hh,
    short8* __restrict__ WB)
{
  int idx = blockIdx.x * 256 + threadIdx.x;
  if (idx >= KSTEPS * 8 * 12 * 64) return;
  int lane = idx & 63;
  int rem  = idx >> 6;
  int f    = rem % 12; rem /= 12;
  int w    = rem & 7;
  int ks   = rem >> 3;
  int g = f >> 2, tt = f & 3;
  int n  = g * 512 + w * 64 + tt * 16 + (lane & 15);
  int k0 = ks * 32 + (lane >> 4) * 8;
  const float* src = (k0 < 128) ? (W_ih + (size_t)n * 128 + k0)
                                : (W_hh + (size_t)n * 512 + (k0 - 128));
  float4 x0 = ((const float4*)src)[0];
  float4 x1 = ((const float4*)src)[1];
  union { unsigned short us[8]; short8 v; } pk;
  pk.us[0] = f2bf(x0.x); pk.us[1] = f2bf(x0.y); pk.us[2] = f2bf(x0.z); pk.us[3] = f2bf(x0.w);
  pk.us[4] = f2bf(x1.x); pk.us[5] = f2bf(x1.y); pk.us[6] = f2bf(x1.z); pk.us[7] = f2bf(x1.w);
  WB[idx] = pk.v;
}

__device__ __forceinline__ void loadB(const short8* __restrict__ p, int ks, short8 B[12]) {
  const short8* q = p + (size_t)ks * 6144;   // 8*12*64 frags per ks
  #pragma unroll
  for (int f = 0; f < 12; ++f) B[f] = q[f * 64];
}

// ---------------------------------------------------------------------------
// Main: 64 blocks x 512 threads (8 waves). Block owns 32 batch rows (2 M-tiles),
// runs all T=512 steps. Wave w owns h-columns [w*64, w*64+64) of each gate.
// B-fragments double-buffered in registers (2 ks-chunks in flight).
// ---------------------------------------------------------------------------
__global__ __launch_bounds__(512, 2) void cru_main(
    const float* __restrict__ values, const float* __restrict__ maskp,
    const float* __restrict__ tsp,
    const float* __restrict__ b_ih, const float* __restrict__ b_hh,
    const float* __restrict__ W_decay, const float* __restrict__ b_decay,
    const float* __restrict__ W_head, const float* __restrict__ b_head,
    const short8* __restrict__ WB,
    float* __restrict__ out)
{
  __shared__ float  sh[BB][SHS];               // fp32 master hidden state (66 KB)
  __shared__ short8 apk[2 * KSTEPS * 64];      // A frags, [mt][ks][lane] (40 KB)
  __shared__ float  sdt[BB];

  const int tid  = threadIdx.x;
  const int b0   = blockIdx.x * BB;
  const int w    = tid >> 6;
  const int lane = tid & 63;
  const int quad = lane >> 4;
  const int lc   = lane & 15;

  for (int i = tid; i < BB * SHS; i += 512) (&sh[0][0])[i] = 0.f;

  // per-thread constants for the 4 col-triples: j = w*64 + k*16 + lc
  float bR[4], bZ[4], bIN[4], bHN[4], wdc[4], bdc[4];
  #pragma unroll
  for (int k = 0; k < 4; ++k) {
    int j = w * 64 + k * 16 + lc;
    bR[k]  = b_ih[j]        + b_hh[j];
    bZ[k]  = b_ih[j + 512]  + b_hh[j + 512];
    bIN[k] = b_ih[j + 1024];
    bHN[k] = b_hh[j + 1024];
    wdc[k] = W_decay[j];
    bdc[k] = b_decay[j];
  }

  const short8* WBw = WB + w * 768 + lane;     // wave-local fragment stream

  __syncthreads();

  short8 Bc[12], Bn[12];

  for (int t = 0; t < Tn; ++t) {
    // issue first two B-chunks before the staging barrier (overlap with A-pack)
    loadB(WBw, 0, Bc);
    loadB(WBw, 1, Bn);

    // ---- stage A fragments: [x(bf16) | h(bf16)], both M-tiles ----
    for (int s = tid; s < 2 * KSTEPS * 64; s += 512) {
      int mt = s / (KSTEPS * 64);
      int r  = s % (KSTEPS * 64);
      int ks = r >> 6, ln = r & 63;
      int m  = mt * 16 + (ln & 15);
      int kg = ks * 32 + (ln >> 4) * 8;
      float4 x0, x1;
      if (ks < 4) {
        const float* src = (kg < 64)
          ? values + ((size_t)(b0 + m) * Tn + t) * Dn + kg
          : maskp  + ((size_t)(b0 + m) * Tn + t) * Dn + (kg - 64);
        x0 = ((const float4*)src)[0];
        x1 = ((const float4*)src)[1];
      } else {
        const float* src = &sh[m][kg - 128];   // sh already carries decay
        x0 = ((const float4*)src)[0];
        x1 = ((const float4*)src)[1];
      }
      union { unsigned short us[8]; short8 v; } pk;
      pk.us[0] = f2bf(x0.x); pk.us[1] = f2bf(x0.y); pk.us[2] = f2bf(x0.z); pk.us[3] = f2bf(x0.w);
      pk.us[4] = f2bf(x1.x); pk.us[5] = f2bf(x1.y); pk.us[6] = f2bf(x1.z); pk.us[7] = f2bf(x1.w);
      apk[s] = pk.v;
    }
    // next-step dt (used in this step's epilogue decay fold)
    if (tid < BB && t + 1 < Tn) {
      size_t rb = (size_t)(b0 + tid) * Tn + t;
      sdt[tid] = tsp[rb + 1] - tsp[rb];
    }
    __syncthreads();

    floatx4 accR[4][2], accZ[4][2], accIN[4][2], accHN[4][2];
    #pragma unroll
    for (int k = 0; k < 4; ++k)
      #pragma unroll
      for (int mt = 0; mt < 2; ++mt) {
        accR[k][mt]  = (floatx4){0.f, 0.f, 0.f, 0.f};
        accZ[k][mt]  = (floatx4){0.f, 0.f, 0.f, 0.f};
        accIN[k][mt] = (floatx4){0.f, 0.f, 0.f, 0.f};
        accHN[k][mt] = (floatx4){0.f, 0.f, 0.f, 0.f};
      }

    // ---- K-loop: double-buffered B, 24 MFMAs per ks ----
    #pragma unroll
    for (int ks = 0; ks < KSTEPS; ++ks) {
      short8* Bu = (ks & 1) ? Bn : Bc;
      short8 A0 = apk[(0 * KSTEPS + ks) * 64 + lane];
      short8 A1 = apk[(1 * KSTEPS + ks) * 64 + lane];
      #pragma unroll
      for (int tt = 0; tt < 4; ++tt) {
        accR[tt][0] = __builtin_amdgcn_mfma_f32_16x16x32_bf16(A0, Bu[tt],     accR[tt][0], 0, 0, 0);
        accR[tt][1] = __builtin_amdgcn_mfma_f32_16x16x32_bf16(A1, Bu[tt],     accR[tt][1], 0, 0, 0);
        accZ[tt][0] = __builtin_amdgcn_mfma_f32_16x16x32_bf16(A0, Bu[4 + tt], accZ[tt][0], 0, 0, 0);
        accZ[tt][1] = __builtin_amdgcn_mfma_f32_16x16x32_bf16(A1, Bu[4 + tt], accZ[tt][1], 0, 0, 0);
        if (ks < 4) {
          accIN[tt][0] = __builtin_amdgcn_mfma_f32_16x16x32_bf16(A0, Bu[8 + tt], accIN[tt][0], 0, 0, 0);
          accIN[tt][1] = __builtin_amdgcn_mfma_f32_16x16x32_bf16(A1, Bu[8 + tt], accIN[tt][1], 0, 0, 0);
        } else {
          accHN[tt][0] = __builtin_amdgcn_mfma_f32_16x16x32_bf16(A0, Bu[8 + tt], accHN[tt][0], 0, 0, 0);
          accHN[tt][1] = __builtin_amdgcn_mfma_f32_16x16x32_bf16(A1, Bu[8 + tt], accHN[tt][1], 0, 0, 0);
        }
      }
      if (ks + 2 < KSTEPS) loadB(WBw, ks + 2, Bu);   // WAR rotation caps depth at 2
    }

    // ---- epilogue: gates + update + next-step decay, all in registers ----
    const bool last = (t == Tn - 1);
    #pragma unroll
    for (int k = 0; k < 4; ++k) {
      int j = w * 64 + k * 16 + lc;
      #pragma unroll
      for (int mt = 0; mt < 2; ++mt) {
        #pragma unroll
        for (int q = 0; q < 4; ++q) {
          int m = mt * 16 + quad * 4 + q;
          float r  = sigm(accR[k][mt][q] + bR[k]);
          float z  = sigm(accZ[k][mt][q] + bZ[k]);
          float nn = tanhfast(accIN[k][mt][q] + bIN[k] + r * (accHN[k][mt][q] + bHN[k]));
          float hnew = (1.f - z) * nn + z * sh[m][j];
          if (!last) {
            float pre = fmaf(sdt[m], wdc[k], bdc[k]);
            hnew *= frcp(1.f + __expf(pre));         // exp(-softplus(pre))
          }
          sh[m][j] = hnew;
        }
      }
    }
    __syncthreads();
  }

  // ---- head: out[b][nt] = h_T . W_head[nt] + b_head[nt] ----
  if (tid < BB * 8) {
    int b = tid >> 3, nt2 = tid & 7;
    float a = b_head[nt2];
    for (int k2 = 0; k2 < Hn; ++k2)
      a = fmaf(sh[b][k2], W_head[(size_t)nt2 * Hn + k2], a);
    out[(size_t)(b0 + b) * 8 + nt2] = a;
  }
}

extern "C" void kernel_launch(void* const* d_in, const int* in_sizes, int n_in,
                              void* d_out, int out_size, void* d_ws, size_t ws_size,
                              hipStream_t stream)
{
  const float* values  = (const float*)d_in[0];
  const float* mask    = (const float*)d_in[1];
  const float* tsp     = (const float*)d_in[2];
  const float* W_ih    = (const float*)d_in[3];
  const float* W_hh    = (const float*)d_in[4];
  const float* b_ih    = (const float*)d_in[5];
  const float* b_hh    = (const float*)d_in[6];
  const float* W_decay = (const float*)d_in[7];
  const float* b_decay = (const float*)d_in[8];
  const float* W_head  = (const float*)d_in[9];
  const float* b_head  = (const float*)d_in[10];
  float* out = (float*)d_out;

  short8* WB = (short8*)d_ws;   // 20*8*12*64 frags * 16 B = 1.97 MB

  int nfrag_total = KSTEPS * 8 * 12 * 64;
  cru_prep<<<(nfrag_total + 255) / 256, 256, 0, stream>>>(W_ih, W_hh, WB);
  cru_main<<<2048 / BB, 512, 0, stream>>>(values, mask, tsp, b_ih, b_hh,
      W_decay, b_decay, W_head, b_head, WB, out);
}